// Round 15
// baseline (269.646 us; speedup 1.0000x reference)
//
#include <hip/hip_runtime.h>
#include <stdint.h>

#define NCAT   919
#define KDIM   400
#define NDIM   100
#define BK     32
#define NSTEP  13                 // ceil(400/32); step 12 has 16 valid k
#define KPAD   408                // bf16 elems; 816 B row = 16B-aligned b128, 2-way banks (free)
#define NROWS  100                // n=6 fragment row-clamp (cols 100..111 never stored)
#define WELEM  (NROWS * KPAD)     // 40800 elems = 81600 B per buffer; x2 = 163200 <= 163840

typedef float  f32x4  __attribute__((ext_vector_type(4)));
typedef __bf16 bf16x8 __attribute__((ext_vector_type(8)));
typedef __bf16 bf16x2 __attribute__((ext_vector_type(2)));

// r7 retry with the ONE fix: __launch_bounds__(512) (min 1 wave/EU).
// r7's __launch_bounds__(512,2) demanded 4 waves/SIMD -> hard 128-VGPR cap ->
// ~60 regs spilled to scratch (its WRITE_SIZE=364MB was spill writebacks).
// LDS=163200B already pins 1 block/CU -> 8 waves/CU = 2/SIMD -> 256-VGPR tier.
__global__ void __launch_bounds__(512)
cat_dense(const float* __restrict__ in, const float* __restrict__ wt,
          const float* __restrict__ bias, float* __restrict__ out)
{
  __shared__ __bf16 wlds[2 * WELEM];     // double-buffered full W_c

  // Persistent: 256 blocks, each owns a CONSECUTIVE category range. XCD-chunked
  // (default XCD = blockIdx%8) so adjacent ranges share an XCD L2 -> output
  // 128B-line edges between categories merge before writeback.
  const int b0 = blockIdx.x;
  const int bb = (b0 & 7) * 32 + (b0 >> 3);
  int       c  = (bb * NCAT) >> 8;
  const int ce = ((bb + 1) * NCAT) >> 8;

  const int tid  = threadIdx.x;
  const int lane = tid & 63;
  const int wave = tid >> 6;
  const int rl   = lane & 15;            // fragment row (A) / col (B/D)
  const int kg   = (lane >> 4) * 8;      // fragment k offset

  const size_t rstride = (size_t)NCAT * KDIM;
  const size_t rowoff  = (size_t)(wave * 32 + rl) * rstride;

  const float* gA0 = in + (size_t)c * KDIM + rowoff;
  const float* gA1 = gA0 + (size_t)16 * rstride;

  f32x4 areg[4][2][2];                   // 4 slots, depth-3 A prefetch
  f32x4 wr0[5], wr1[5];                  // one W half (10 loads) in flight at a time
  f32x4 acc[2][7];

#define LOADA_G(S, TT, A0, A1) do {                                        \
    const int kb_ = (TT) * BK + kg;                                        \
    if (kb_ + 8 <= KDIM) {   /* per-lane K-tail mask (t=12, kg>=16) */     \
      areg[S][0][0] = *(const f32x4*)((A0) + kb_);                         \
      areg[S][0][1] = *(const f32x4*)((A0) + kb_ + 4);                     \
      areg[S][1][0] = *(const f32x4*)((A1) + kb_);                         \
      areg[S][1][1] = *(const f32x4*)((A1) + kb_ + 4);                     \
    } else {                                                               \
      areg[S][0][0] = f32x4{0,0,0,0}; areg[S][0][1] = f32x4{0,0,0,0};      \
      areg[S][1][0] = f32x4{0,0,0,0}; areg[S][1][1] = f32x4{0,0,0,0};      \
    }                                                                      \
  } while (0)

  // W staging split in halves: pc = kp*25 + nq (nq-sweep: coalesced 400B
  // global runs); half H covers pc in [2560H, 2560H+2560) (guarded < 5000).
#define WLOAD_HALF(H, GWP) do {                                            \
    _Pragma("unroll")                                                      \
    for (int i_ = 0; i_ < 5; ++i_) {                                       \
      const int pc_ = tid + ((H) * 5 + i_) * 512;                          \
      if (pc_ < 5000) {                                                    \
        const int kp_ = pc_ / 25;                                          \
        const int nq_ = pc_ - kp_ * 25;                                    \
        const float* p_ = (GWP) + (size_t)(kp_ * 2) * NDIM + nq_ * 4;      \
        wr0[i_] = *(const f32x4*)p_;                                       \
        wr1[i_] = *(const f32x4*)(p_ + NDIM);                              \
      }                                                                    \
    }                                                                      \
  } while (0)

#define WWRITE_HALF(H, DST) do {                                           \
    _Pragma("unroll")                                                      \
    for (int i_ = 0; i_ < 5; ++i_) {                                       \
      const int pc_ = tid + ((H) * 5 + i_) * 512;                          \
      if (pc_ < 5000) {                                                    \
        const int kp_ = pc_ / 25;                                          \
        const int nq_ = pc_ - kp_ * 25;                                    \
        const int k_  = kp_ * 2;                                           \
        _Pragma("unroll")                                                  \
        for (int j_ = 0; j_ < 4; ++j_) {                                   \
          bf16x2 pk_ = { (__bf16)wr0[i_][j_], (__bf16)wr1[i_][j_] };       \
          *(bf16x2*)&(DST)[(nq_ * 4 + j_) * KPAD + k_] = pk_;              \
        }                                                                  \
      }                                                                    \
    }                                                                      \
  } while (0)

  // ---- prologue (once per block): A(0..2) + cold-stage W(c) into buf 0 ----
  LOADA_G(0, 0, gA0, gA1);
  LOADA_G(1, 1, gA0, gA1);
  LOADA_G(2, 2, gA0, gA1);
  {
    const float* gW = wt + (size_t)c * (KDIM * NDIM);
    WLOAD_HALF(0, gW);  WWRITE_HALF(0, (&wlds[0]));
    WLOAD_HALF(1, gW);  WWRITE_HALF(1, (&wlds[0]));
  }
  __syncthreads();

  #pragma unroll
  for (int m = 0; m < 2; ++m)
    #pragma unroll
    for (int n = 0; n < 7; ++n) acc[m][n] = f32x4{0,0,0,0};

  // ---- persistent category loop ----
  for (int it = 0; ; ++it) {
    const bool hasnext = (c + 1 < ce);                    // block-uniform
    const int  cn      = hasnext ? c + 1 : c;
    const float* gA0n  = in + (size_t)cn * KDIM + rowoff;
    const float* gA1n  = gA0n + (size_t)16 * rstride;
    const float* gWn   = wt + (size_t)cn * (KDIM * NDIM);
    const __bf16* R    = &wlds[(it & 1) * WELEM];         // compute from this buf
    __bf16*       Wb   = &wlds[((it & 1) ^ 1) * WELEM];   // stage next cat here

    if (hasnext) WLOAD_HALF(0, gWn);   // 10 loads in flight across steps 0..5

    #pragma unroll
    for (int t = 0; t < NSTEP; ++t) {
      const int pp = t & 3;
      bf16x8 a0, a1;
      #pragma unroll
      for (int j = 0; j < 4; ++j) {    // vmcnt wait for A(t) lands here
        a0[j]     = (__bf16)areg[pp][0][0][j];
        a0[4 + j] = (__bf16)areg[pp][0][1][j];
        a1[j]     = (__bf16)areg[pp][1][0][j];
        a1[4 + j] = (__bf16)areg[pp][1][1][j];
      }
      // cvt FIRST, then refill slots (t==12 refills the slot cvt just read)
      if (t <= 9)               LOADA_G((t + 3) & 3, t + 3, gA0, gA1);
      if (t == 6 && hasnext) { WWRITE_HALF(0, Wb); WLOAD_HALF(1, gWn); }
      if (t == 10 && hasnext) { LOADA_G(1, 1, gA0n, gA1n);
                                LOADA_G(2, 2, gA0n, gA1n); }
      if (t == 12 && hasnext) { LOADA_G(0, 0, gA0n, gA1n); }

      // K-clamp: lanes that clamp (t=12, kg>=16) have A==0 -> finite B suffices.
      const int kb2  = t * BK + kg;
      const int koff = (kb2 <= KDIM - 8) ? kb2 : (KDIM - 8);
      #pragma unroll
      for (int n = 0; n < 7; ++n) {
        // n=6 row-clamp: cols 96..99 (rl<4) true rows; cols>=100 never stored.
        // Duplicate-row lanes read the SAME address -> LDS broadcast, free.
        const int brow = n * 16 + (n == 6 ? (rl & 3) : rl);
        bf16x8 b = *(const bf16x8*)&R[brow * KPAD + koff];
        acc[0][n] = __builtin_amdgcn_mfma_f32_16x16x32_bf16(a0, b, acc[0][n], 0,0,0);
        acc[1][n] = __builtin_amdgcn_mfma_f32_16x16x32_bf16(a1, b, acc[1][n], 0,0,0);
      }
    }

    if (hasnext) {
      WWRITE_HALF(1, Wb);     // W half2 arrived during steps 6..12
      __syncthreads();        // Wb complete; all waves done reading R
    }

    // ---- epilogue for c: C/D map col = lane&15, row = (lane>>4)*4 + reg ----
    {
      const float* gB = bias + (size_t)c * NDIM;
      float* gO = out + (size_t)c * NDIM;
      #pragma unroll
      for (int n = 0; n < 7; ++n) {
        const int col = n * 16 + rl;
        if (col < NDIM) {
          const float bv = gB[col];
          #pragma unroll
          for (int m = 0; m < 2; ++m) {
            const int r0 = wave * 32 + m * 16 + (lane >> 4) * 4;
            #pragma unroll
            for (int j = 0; j < 4; ++j)
              gO[(size_t)(r0 + j) * ((size_t)NCAT * NDIM) + col] = acc[m][n][j] + bv;
          }
        }
      }
    }

    if (!hasnext) break;
    #pragma unroll
    for (int m = 0; m < 2; ++m)
      #pragma unroll
      for (int n = 0; n < 7; ++n) acc[m][n] = f32x4{0,0,0,0};
    gA0 = gA0n; gA1 = gA1n; c = cn;
  }
}

extern "C" void kernel_launch(void* const* d_in, const int* in_sizes, int n_in,
                              void* d_out, int out_size, void* d_ws, size_t ws_size,
                              hipStream_t stream) {
  const float* in   = (const float*)d_in[0];
  const float* wt   = (const float*)d_in[1];
  const float* bias = (const float*)d_in[2];
  float* o          = (float*)d_out;
  cat_dense<<<dim3(256), dim3(512), 0, stream>>>(in, wt, bias, o);
}

// Round 16
// 144.376 us; speedup vs baseline: 1.8677x; 1.8677x over previous
//
#include <hip/hip_runtime.h>
#include <stdint.h>

#define NCAT  919
#define KDIM  400
#define NDIM  100
#define BK    32
#define NSTEP 13                 // ceil(400/32); step 12 has 16 valid k
#define KPAD  408                // bf16; row = 816 B (16B-aligned b128; read banks 2-way free)
#define NROWS 100                // n=6 fragment row-clamps; cols 100..111 never stored
                                 // LDS = 100*408*2 = 81600 B

typedef float  f32x4  __attribute__((ext_vector_type(4)));
typedef __bf16 bf16x8 __attribute__((ext_vector_type(8)));
typedef __bf16 bf16x2 __attribute__((ext_vector_type(2)));

__global__ void __launch_bounds__(512, 2)
cat_dense(const float* __restrict__ in, const float* __restrict__ wt,
          const float* __restrict__ bias, float* __restrict__ out)
{
  __shared__ __bf16 wlds[NROWS * KPAD];

  // Bijective XCD-aware swizzle (m204): 919 = 7*115 + 114. Consecutive categories
  // share an XCD L2 -> partial 128B output lines merge before writeback.
  const int ob   = blockIdx.x;
  const int xcd  = ob & 7;
  const int bidx = ob >> 3;
  const int c    = (xcd < 7 ? xcd * 115 : 805 + (xcd - 7) * 114) + bidx;

  const int tid  = threadIdx.x;
  const int lane = tid & 63;
  const int wave = tid >> 6;
  const int rl   = lane & 15;                // fragment row (A) / col (B/D)
  const int kg   = (lane >> 4) * 8;          // fragment k offset

  const size_t rstride = (size_t)NCAT * KDIM;
  const float* gA0 = in + (size_t)c * KDIM + (size_t)(wave * 32 + rl) * rstride;
  const float* gA1 = gA0 + (size_t)16 * rstride;
  const float* gW  = wt + (size_t)c * (KDIM * NDIM);

  // 6 A-prefetch slots (96 VGPR). Bursts of two steps (256B/row page runs,
  // r9-proven) at t=0,2,4; singles at t=8 (A10,A11: AFTER barrier-2) and t=9.
  // Slot T%6: always consumed >=2 steps before rewrite (verified schedule).
  f32x4 areg[6][2][2];

#define LOADA(T) do {                                                      \
    const int kb_ = (T) * BK + kg;                                         \
    if (kb_ + 8 <= KDIM) {   /* per-lane K-tail mask (step 12, kg>=16) */  \
      areg[(T) % 6][0][0] = *(const f32x4*)(gA0 + kb_);                    \
      areg[(T) % 6][0][1] = *(const f32x4*)(gA0 + kb_ + 4);                \
      areg[(T) % 6][1][0] = *(const f32x4*)(gA1 + kb_);                    \
      areg[(T) % 6][1][1] = *(const f32x4*)(gA1 + kb_ + 4);                \
    } else {                                                               \
      areg[(T) % 6][0][0] = f32x4{0,0,0,0};                                \
      areg[(T) % 6][0][1] = f32x4{0,0,0,0};                                \
      areg[(T) % 6][1][0] = f32x4{0,0,0,0};                                \
      areg[(T) % 6][1][1] = f32x4{0,0,0,0};                                \
    }                                                                      \
  } while (0)

  // ---- prologue: 4 A-steps + bias in flight; they land during W staging ----
  LOADA(0); LOADA(1); LOADA(2); LOADA(3);

  // Bias hoisted: kills the epilogue load->add->store latency chain.
  const float* gB = bias + (size_t)c * NDIM;
  float bv[7];
  #pragma unroll
  for (int n = 0; n < 7; ++n) {
    const int col = n * 16 + rl;
    bv[n] = (col < NDIM) ? gB[col] : 0.f;
  }

  // ---- W stage half 1: kp < 128 (k < 256), nq-SWEEP mapping (r9-proven:
  // consecutive lanes sweep nq -> 400B coalesced global runs). Load-all-
  // then-write-all so the HBM round-trips overlap instead of chaining.
  f32x4 wa0[7], wa1[7];
  #pragma unroll
  for (int i = 0; i < 7; ++i) {
    const int pc = tid + i * 512;              // pc = kp*25 + nq, kp<128
    if (pc < 3200) {
      const int kp = pc / 25;
      const int nq = pc - kp * 25;
      const float* p = gW + (size_t)(2 * kp) * NDIM + nq * 4;
      wa0[i] = *(const f32x4*)p;
      wa1[i] = *(const f32x4*)(p + NDIM);
    }
  }
  #pragma unroll
  for (int i = 0; i < 7; ++i) {
    const int pc = tid + i * 512;
    if (pc < 3200) {
      const int kp = pc / 25;
      const int nq = pc - kp * 25;
      #pragma unroll
      for (int j = 0; j < 4; ++j) {
        bf16x2 pk = { (__bf16)wa0[i][j], (__bf16)wa1[i][j] };
        *(bf16x2*)&wlds[(nq * 4 + j) * KPAD + 2 * kp] = pk;
      }
    }
  }
  // Barrier 1: k<256 visible. __syncthreads = real fence (round-4 lesson).
  __syncthreads();

  // ---- W stage half 2: kp in [128,200) (k in [256,400)). ISSUE loads now;
  // they land under compute t=0..7. Only 8 f32x4 (32 VGPR) held live.
  f32x4 wb0[4], wb1[4];
  #pragma unroll
  for (int i = 0; i < 4; ++i) {
    const int pc = tid + i * 512;              // pc = (kp-128)*25 + nq
    if (pc < 1800) {
      const int kp = 128 + pc / 25;
      const int nq = pc - (kp - 128) * 25;
      const float* p = gW + (size_t)(2 * kp) * NDIM + nq * 4;
      wb0[i] = *(const f32x4*)p;
      wb1[i] = *(const f32x4*)(p + NDIM);
    }
  }
  // Pin program order: don't let the scheduler sink these to their t==7 use
  // (round-7 failure mode under register pressure).
  __builtin_amdgcn_sched_barrier(0);

  f32x4 acc[2][7];
  #pragma unroll
  for (int m = 0; m < 2; ++m)
    #pragma unroll
    for (int n = 0; n < 7; ++n) acc[m][n] = f32x4{0, 0, 0, 0};

  // ---- main loop: t=0..7 read k<256; write half-2 + barrier at end of t=7;
  // t=8..12 read k>=256. ----
  #pragma unroll
  for (int t = 0; t < NSTEP; ++t) {
    const int pp = t % 6;
    bf16x8 a0, a1;
    #pragma unroll
    for (int j = 0; j < 4; ++j) {              // vmcnt wait for A(t) lands here
      a0[j]     = (__bf16)areg[pp][0][0][j];
      a0[4 + j] = (__bf16)areg[pp][0][1][j];
      a1[j]     = (__bf16)areg[pp][1][0][j];
      a1[4 + j] = (__bf16)areg[pp][1][1][j];
    }
    // A-prefetch: 256B page bursts; t=8 issues come AFTER barrier-2 so the
    // mid-loop __syncthreads never drains a just-issued load (in-flight there:
    // A8,A9 issued at t=4 — long arrived).
    if (t == 0 || t == 2 || t == 4) { LOADA(t + 4); LOADA(t + 5); }
    if (t == 8)                     { LOADA(10);    LOADA(11);    }
    if (t == 9)                     { LOADA(12);                  }

    // K-clamp: lanes that clamp (t=12, kg>=16) have A==0 -> finite B suffices.
    const int kb2  = t * BK + kg;
    const int koff = (kb2 <= KDIM - 8) ? kb2 : (KDIM - 8);
    #pragma unroll
    for (int n = 0; n < 7; ++n) {
      // n=6 row-clamp: cols 96..99 (rl<4) get true rows; cols>=100 never
      // stored; clamped lanes read identical addresses -> LDS broadcast.
      const int brow = n * 16 + (n == 6 ? (rl & 3) : rl);
      bf16x8 b = *(const bf16x8*)&wlds[brow * KPAD + koff];
      acc[0][n] = __builtin_amdgcn_mfma_f32_16x16x32_bf16(a0, b, acc[0][n], 0, 0, 0);
      acc[1][n] = __builtin_amdgcn_mfma_f32_16x16x32_bf16(a1, b, acc[1][n], 0, 0, 0);
    }

    if (t == 7) {
      // Half-2 loads arrived during t=0..7; write + barrier 2.
      #pragma unroll
      for (int i = 0; i < 4; ++i) {
        const int pc = tid + i * 512;
        if (pc < 1800) {
          const int kp = 128 + pc / 25;
          const int nq = pc - (kp - 128) * 25;
          #pragma unroll
          for (int j = 0; j < 4; ++j) {
            bf16x2 pk = { (__bf16)wb0[i][j], (__bf16)wb1[i][j] };
            *(bf16x2*)&wlds[(nq * 4 + j) * KPAD + 2 * kp] = pk;
          }
        }
      }
      __syncthreads();
    }
  }

  // ---- epilogue: C/D map (16x16 family): col = lane&15, row = (lane>>4)*4 + reg ----
  float* gO = out + (size_t)c * NDIM;
  #pragma unroll
  for (int n = 0; n < 7; ++n) {
    const int col = n * 16 + rl;
    if (col < NDIM) {
      #pragma unroll
      for (int m = 0; m < 2; ++m) {
        const int r0 = wave * 32 + m * 16 + (lane >> 4) * 4;
        #pragma unroll
        for (int j = 0; j < 4; ++j) {
          gO[(size_t)(r0 + j) * ((size_t)NCAT * NDIM) + col] = acc[m][n][j] + bv[n];
        }
      }
    }
  }
}

extern "C" void kernel_launch(void* const* d_in, const int* in_sizes, int n_in,
                              void* d_out, int out_size, void* d_ws, size_t ws_size,
                              hipStream_t stream) {
  const float* in   = (const float*)d_in[0];
  const float* wt   = (const float*)d_in[1];
  const float* bias = (const float*)d_in[2];
  float* o          = (float*)d_out;
  cat_dense<<<dim3(NCAT), dim3(512), 0, stream>>>(in, wt, bias, o);
}